// Round 1
// baseline (473.043 us; speedup 1.0000x reference)
//
#include <hip/hip_runtime.h>
#include <math.h>

#define NB 8
#define HH 256
#define WW 256
#define HW (HH*WW)

// ---- workspace layout (float offsets) ----
#define OFF_FEATS 0                          // [NB][12][HH][WW]
#define OFF_X1    (OFF_FEATS + NB*12*HW)     // [NB][32][HH][WW]
#define OFF_AFF   (OFF_X1    + NB*32*HW)     // [NB][8][HH][WW]
#define OFF_W1T   (OFF_AFF   + NB*8*HW)      // [108][32]  (BN-folded)
#define OFF_B1F   (OFF_W1T   + 108*32)       // [32]
#define OFF_W2T   (OFF_B1F   + 32)           // [288][64]  (BN-folded)
#define OFF_B2F   (OFF_W2T   + 288*64)       // [64]
#define WS_TOTAL  (OFF_B2F   + 64)           // ~104 MB

// ---------------- prep: fold BN into transposed conv weights ----------------
__global__ __launch_bounds__(256) void prep_weights(
    const float* __restrict__ w1, const float* __restrict__ g1,
    const float* __restrict__ b1, const float* __restrict__ m1,
    const float* __restrict__ v1,
    const float* __restrict__ w2, const float* __restrict__ g2,
    const float* __restrict__ b2, const float* __restrict__ m2,
    const float* __restrict__ v2,
    float* __restrict__ ws) {
  int idx = blockIdx.x * 256 + threadIdx.x;
  float* w1t = ws + OFF_W1T;
  float* b1f = ws + OFF_B1F;
  float* w2t = ws + OFF_W2T;
  float* b2f = ws + OFF_B2F;
  if (idx < 108 * 32) {
    int kk = idx >> 5, o = idx & 31;
    int cin = kk / 9, r = kk - cin * 9;
    float inv = g1[o] / sqrtf(v1[o] + 1e-5f);
    w1t[idx] = w1[(o * 12 + cin) * 9 + r] * inv;
    if (kk == 0) b1f[o] = b1[o] - m1[o] * inv;
  }
  int j = idx - 108 * 32;
  if (j >= 0 && j < 288 * 64) {
    int kk = j >> 6, o = j & 63;
    int cin = kk / 9, r = kk - cin * 9;
    float inv = g2[o] / sqrtf(v2[o] + 1e-5f);
    w2t[j] = w2[(o * 32 + cin) * 9 + r] * inv;
    if (kk == 0) b2f[o] = b2[o] - m2[o] * inv;
  }
}

// ---------------- feats: resize(2x box) + lr-warp error + concat ----------------
__device__ __forceinline__ float avg4(const float* __restrict__ img, int n, int c,
                                      int i2, int x) {
  const float* p = img + ((size_t)(n * 3 + c) * 512 + i2) * 512 + 2 * x;
  return 0.25f * (p[0] + p[1] + p[512] + p[513]);
}

__global__ __launch_bounds__(256) void build_feats(
    const float* __restrict__ normal, const float* __restrict__ left,
    const float* __restrict__ right, const float* __restrict__ disp,
    float* __restrict__ ws) {
  int gid = blockIdx.x * 256 + threadIdx.x;
  int n = gid / HW;
  int r = gid - n * HW;
  int i = r / WW;
  int j = r - i * WW;
  float* feats = ws + OFF_FEATS;
  int base = n * 12 * HW + i * WW + j;
#pragma unroll
  for (int c = 0; c < 3; ++c)
    feats[base + c * HW] = normal[(size_t)(n * 3 + c) * HW + i * WW + j];
  int i2 = 2 * i;
  float cl[3], cr[3];
#pragma unroll
  for (int c = 0; c < 3; ++c) {
    cl[c] = avg4(left, n, c, i2, j);
    cr[c] = avg4(right, n, c, i2, j);
    feats[base + (3 + c) * HW] = cl[c];
    feats[base + (6 + c) * HW] = cr[c];
  }
  float d = disp[n * HW + i * WW + j];
  float xs = (float)j - d;
  float x0f = floorf(xs);
  float fr = xs - x0f;
  int x0 = (int)x0f;
  int x1 = x0 + 1;
  float v0 = (x0 >= 0 && x0 < WW) ? 1.f : 0.f;
  float v1 = (x1 >= 0 && x1 < WW) ? 1.f : 0.f;
  int x0c = min(max(x0, 0), WW - 1);
  int x1c = min(max(x1, 0), WW - 1);
#pragma unroll
  for (int c = 0; c < 3; ++c) {
    float gg0 = avg4(right, n, c, i2, x0c) * v0;
    float gg1 = avg4(right, n, c, i2, x1c) * v1;
    float warped = gg0 * (1.f - fr) + gg1 * fr;
    feats[base + (9 + c) * HW] = fabsf(cl[c] - warped);
  }
}

// ---------------- conv1: 3x3 12->32 + BN + ReLU ----------------
__global__ __launch_bounds__(256) void conv1_kernel(float* __restrict__ ws) {
  __shared__ float sIn[12 * 18 * 18];
  const float* feats = ws + OFF_FEATS;
  const float* __restrict__ w1t = ws + OFF_W1T;
  const float* __restrict__ b1f = ws + OFF_B1F;
  float* x1 = ws + OFF_X1;
  int blk = blockIdx.x;
  int n = blk >> 8;
  int t = blk & 255;
  int ty0 = (t >> 4) << 4;
  int tx0 = (t & 15) << 4;
  int tid = threadIdx.x;
  for (int e = tid; e < 12 * 18 * 18; e += 256) {
    int c = e / 324;
    int rr = e - c * 324;
    int y = rr / 18;
    int x = rr - y * 18;
    int gy = ty0 + y - 1, gx = tx0 + x - 1;
    float v = 0.f;
    if (gy >= 0 && gy < HH && gx >= 0 && gx < WW)
      v = feats[(size_t)(n * 12 + c) * HW + gy * WW + gx];
    sIn[e] = v;
  }
  __syncthreads();
  int tx = tid & 15, ty = tid >> 4;
  float acc[32];
#pragma unroll
  for (int o = 0; o < 32; ++o) acc[o] = b1f[o];
  for (int cin = 0; cin < 12; ++cin) {
#pragma unroll
    for (int ky = 0; ky < 3; ++ky) {
#pragma unroll
      for (int kx = 0; kx < 3; ++kx) {
        float v = sIn[cin * 324 + (ty + ky) * 18 + tx + kx];
        const float* __restrict__ wr = w1t + (cin * 9 + ky * 3 + kx) * 32;
#pragma unroll
        for (int o = 0; o < 32; ++o) acc[o] = fmaf(v, wr[o], acc[o]);
      }
    }
  }
  int ob = n * 32 * HW + (ty0 + ty) * WW + tx0 + tx;
#pragma unroll
  for (int o = 0; o < 32; ++o) x1[ob + o * HW] = fmaxf(acc[o], 0.f);
}

// ---------------- conv2: 3x3 32->64 + BN + ReLU, fused conv3 1x1 64->8 + ReLU ----------------
__global__ __launch_bounds__(256) void conv2_kernel(float* __restrict__ ws,
                                                    const float* __restrict__ w3) {
  __shared__ float sIn[32 * 18 * 18];  // 40.5 KB
  const float* x1 = ws + OFF_X1;
  const float* __restrict__ w2t = ws + OFF_W2T;
  const float* __restrict__ b2f = ws + OFF_B2F;
  float* aff = ws + OFF_AFF;
  int blk = blockIdx.x;
  int n = blk >> 8;
  int t = blk & 255;
  int ty0 = (t >> 4) << 4;
  int tx0 = (t & 15) << 4;
  int tid = threadIdx.x;
  for (int e = tid; e < 32 * 18 * 18; e += 256) {
    int c = e / 324;
    int rr = e - c * 324;
    int y = rr / 18;
    int x = rr - y * 18;
    int gy = ty0 + y - 1, gx = tx0 + x - 1;
    float v = 0.f;
    if (gy >= 0 && gy < HH && gx >= 0 && gx < WW)
      v = x1[(size_t)(n * 32 + c) * HW + gy * WW + gx];
    sIn[e] = v;
  }
  __syncthreads();
  int tx = tid & 15, ty = tid >> 4;
  float acc[64];
#pragma unroll
  for (int o = 0; o < 64; ++o) acc[o] = b2f[o];
  for (int cin = 0; cin < 32; ++cin) {
#pragma unroll
    for (int ky = 0; ky < 3; ++ky) {
#pragma unroll
      for (int kx = 0; kx < 3; ++kx) {
        float v = sIn[cin * 324 + (ty + ky) * 18 + tx + kx];
        const float* __restrict__ wr = w2t + (cin * 9 + ky * 3 + kx) * 64;
#pragma unroll
        for (int o = 0; o < 64; ++o) acc[o] = fmaf(v, wr[o], acc[o]);
      }
    }
  }
#pragma unroll
  for (int o = 0; o < 64; ++o) acc[o] = fmaxf(acc[o], 0.f);
  int ob = n * 8 * HW + (ty0 + ty) * WW + tx0 + tx;
#pragma unroll
  for (int k = 0; k < 8; ++k) {
    float s = 0.f;
#pragma unroll
    for (int o = 0; o < 64; ++o) s = fmaf(acc[o], w3[k * 64 + o], s);
    aff[ob + k * HW] = fmaxf(s, 0.f);
  }
}

// ---------------- final: 8-neighbor softmax-gated propagation ----------------
__global__ __launch_bounds__(256) void final_kernel(const float* __restrict__ disp,
                                                    const float* __restrict__ ws,
                                                    float* __restrict__ out) {
  int gid = blockIdx.x * 256 + threadIdx.x;
  int n = gid / HW;
  int r = gid - n * HW;
  int i = r / WW;
  int j = r - i * WW;
  const float* aff = ws + OFF_AFF;
  const int dy[8] = {1, 1, 1, 0, 0, -1, -1, -1};
  const int dx[8] = {1, 0, -1, 1, -1, 1, 0, -1};
  float g[8], dv[8];
#pragma unroll
  for (int k = 0; k < 8; ++k) {
    int y = i + dy[k], x = j + dx[k];
    bool ok = (y >= 0 && y < HH && x >= 0 && x < WW);
    g[k] = ok ? aff[(size_t)(n * 8 + k) * HW + y * WW + x] : 0.f;
    dv[k] = ok ? disp[n * HW + y * WW + x] : 0.f;
  }
  float m = g[0];
#pragma unroll
  for (int k = 1; k < 8; ++k) m = fmaxf(m, g[k]);
  float se = 0.f, sed = 0.f;
#pragma unroll
  for (int k = 0; k < 8; ++k) {
    float e = __expf(g[k] - m);
    se += e;
    sed += e * dv[k];
  }
  float dc = disp[n * HW + i * WW + j];
  out[gid] = 0.3f * (sed / se) + 0.7f * dc;
}

extern "C" void kernel_launch(void* const* d_in, const int* in_sizes, int n_in,
                              void* d_out, int out_size, void* d_ws, size_t ws_size,
                              hipStream_t stream) {
  const float* normal = (const float*)d_in[0];
  const float* left   = (const float*)d_in[1];
  const float* right  = (const float*)d_in[2];
  const float* disp   = (const float*)d_in[3];
  const float* w1 = (const float*)d_in[4];
  const float* g1 = (const float*)d_in[5];
  const float* b1 = (const float*)d_in[6];
  const float* m1 = (const float*)d_in[7];
  const float* v1 = (const float*)d_in[8];
  const float* w2 = (const float*)d_in[9];
  const float* g2 = (const float*)d_in[10];
  const float* b2 = (const float*)d_in[11];
  const float* m2 = (const float*)d_in[12];
  const float* v2 = (const float*)d_in[13];
  const float* w3 = (const float*)d_in[14];
  float* ws  = (float*)d_ws;
  float* out = (float*)d_out;

  hipLaunchKernelGGL(prep_weights, dim3(86), dim3(256), 0, stream,
                     w1, g1, b1, m1, v1, w2, g2, b2, m2, v2, ws);
  hipLaunchKernelGGL(build_feats, dim3(2048), dim3(256), 0, stream,
                     normal, left, right, disp, ws);
  hipLaunchKernelGGL(conv1_kernel, dim3(2048), dim3(256), 0, stream, ws);
  hipLaunchKernelGGL(conv2_kernel, dim3(2048), dim3(256), 0, stream, ws, w3);
  hipLaunchKernelGGL(final_kernel, dim3(2048), dim3(256), 0, stream, disp, ws, out);
}

// Round 2
// 221.182 us; speedup vs baseline: 2.1387x; 2.1387x over previous
//
#include <hip/hip_runtime.h>
#include <math.h>

#define NB 8
#define HH 256
#define WW 256
#define HW (HH*WW)

// ---- workspace layout (BYTE offsets) ----
#define OFF_FEATS 0UL                 // [8][12][256][256] fp32   (25165824 B)
#define OFF_X1B   25165824UL          // [8][256][256][32] bf16   (33554432 B)
#define OFF_AFFB  58720256UL          // [8][8][256][256]  fp32   (16777216 B)
#define OFF_W1TB  75497472UL          // [108][32] fp32 BN-folded (13824 B)
#define OFF_B1FB  75511296UL          // [32] fp32
#define OFF_W2FB  75511424UL          // [18432] bf16, MFMA B-fragment order
#define OFF_B2FB  75548288UL          // [64] fp32

typedef short  short8 __attribute__((ext_vector_type(8)));
typedef ushort u16x8  __attribute__((ext_vector_type(8)));
typedef float  f32x4  __attribute__((ext_vector_type(4)));

__device__ __forceinline__ ushort f2bf(float x) {
  uint u = __float_as_uint(x);
  return (ushort)((u + 0x7FFFu + ((u >> 16) & 1u)) >> 16);
}
__device__ __forceinline__ float bf2f(ushort h) {
  uint u = ((uint)h) << 16;
  return __uint_as_float(u);
}

// ---------------- prep: fold BN; w1t fp32 transposed; w2 -> bf16 B-fragment order ----------------
__global__ __launch_bounds__(256) void prep_weights(
    const float* __restrict__ w1, const float* __restrict__ g1,
    const float* __restrict__ b1, const float* __restrict__ m1,
    const float* __restrict__ v1,
    const float* __restrict__ w2, const float* __restrict__ g2,
    const float* __restrict__ b2, const float* __restrict__ m2,
    const float* __restrict__ v2,
    char* __restrict__ wsb) {
  int idx = blockIdx.x * 256 + threadIdx.x;
  float* w1t  = (float*)(wsb + OFF_W1TB);
  float* b1f  = (float*)(wsb + OFF_B1FB);
  ushort* w2f = (ushort*)(wsb + OFF_W2FB);
  float* b2f  = (float*)(wsb + OFF_B2FB);
  if (idx < 108 * 32) {
    int kk = idx >> 5, o = idx & 31;
    int cin = kk / 9, r = kk - cin * 9;
    float inv = g1[o] / sqrtf(v1[o] + 1e-5f);
    w1t[idx] = w1[(o * 12 + cin) * 9 + r] * inv;
    if (kk == 0) b1f[o] = b1[o] - m1[o] * inv;
  }
  int j = idx - 108 * 32;
  if (j >= 0 && j < 18432) {
    int kk   = j >> 11;          // 0..8
    int nt   = (j >> 9) & 3;     // 0..3
    int lane = (j >> 3) & 63;    // 0..63
    int jj   = j & 7;            // 0..7
    int q  = lane >> 4, lx = lane & 15;
    int cin = q * 8 + jj;        // 0..31
    int out = nt * 16 + lx;      // 0..63
    float inv = g2[out] / sqrtf(v2[out] + 1e-5f);
    w2f[j] = f2bf(w2[(out * 32 + cin) * 9 + kk] * inv);
    if (kk == 0 && q == 0 && jj == 0) b2f[out] = b2[out] - m2[out] * inv;
  }
}

// ---------------- feats: resize(2x box) + lr-warp error + concat ----------------
__device__ __forceinline__ float avg4(const float* __restrict__ img, int n, int c,
                                      int i2, int x) {
  const float* p = img + ((size_t)(n * 3 + c) * 512 + i2) * 512 + 2 * x;
  return 0.25f * (p[0] + p[1] + p[512] + p[513]);
}

__global__ __launch_bounds__(256) void build_feats(
    const float* __restrict__ normal, const float* __restrict__ left,
    const float* __restrict__ right, const float* __restrict__ disp,
    char* __restrict__ wsb) {
  int gid = blockIdx.x * 256 + threadIdx.x;
  int n = gid / HW;
  int r = gid - n * HW;
  int i = r / WW;
  int j = r - i * WW;
  float* feats = (float*)(wsb + OFF_FEATS);
  int base = n * 12 * HW + i * WW + j;
#pragma unroll
  for (int c = 0; c < 3; ++c)
    feats[base + c * HW] = normal[(size_t)(n * 3 + c) * HW + i * WW + j];
  int i2 = 2 * i;
  float cl[3];
#pragma unroll
  for (int c = 0; c < 3; ++c) {
    cl[c] = avg4(left, n, c, i2, j);
    float cr = avg4(right, n, c, i2, j);
    feats[base + (3 + c) * HW] = cl[c];
    feats[base + (6 + c) * HW] = cr;
  }
  float d = disp[n * HW + i * WW + j];
  float xs = (float)j - d;
  float x0f = floorf(xs);
  float fr = xs - x0f;
  int x0 = (int)x0f;
  int x1 = x0 + 1;
  float v0 = (x0 >= 0 && x0 < WW) ? 1.f : 0.f;
  float v1 = (x1 >= 0 && x1 < WW) ? 1.f : 0.f;
  int x0c = min(max(x0, 0), WW - 1);
  int x1c = min(max(x1, 0), WW - 1);
#pragma unroll
  for (int c = 0; c < 3; ++c) {
    float gg0 = avg4(right, n, c, i2, x0c) * v0;
    float gg1 = avg4(right, n, c, i2, x1c) * v1;
    float warped = gg0 * (1.f - fr) + gg1 * fr;
    feats[base + (9 + c) * HW] = fabsf(cl[c] - warped);
  }
}

// ---------------- conv1: 3x3 12->32 + BN + ReLU (fp32 VALU), writes NHWC bf16 ----------------
__global__ __launch_bounds__(256) void conv1_kernel(char* __restrict__ wsb) {
  __shared__ float sIn[12 * 18 * 18];
  const float* feats = (const float*)(wsb + OFF_FEATS);
  const float* __restrict__ w1t = (const float*)(wsb + OFF_W1TB);
  const float* __restrict__ b1f = (const float*)(wsb + OFF_B1FB);
  ushort* x1 = (ushort*)(wsb + OFF_X1B);
  int blk = blockIdx.x;
  int n = blk >> 8;
  int t = blk & 255;
  int ty0 = (t >> 4) << 4;
  int tx0 = (t & 15) << 4;
  int tid = threadIdx.x;
  for (int e = tid; e < 12 * 18 * 18; e += 256) {
    int c = e / 324;
    int rr = e - c * 324;
    int y = rr / 18;
    int x = rr - y * 18;
    int gy = ty0 + y - 1, gx = tx0 + x - 1;
    float v = 0.f;
    if (gy >= 0 && gy < HH && gx >= 0 && gx < WW)
      v = feats[(size_t)(n * 12 + c) * HW + gy * WW + gx];
    sIn[e] = v;
  }
  __syncthreads();
  int tx = tid & 15, ty = tid >> 4;
  float acc[32];
#pragma unroll
  for (int o = 0; o < 32; ++o) acc[o] = b1f[o];
  for (int cin = 0; cin < 12; ++cin) {
#pragma unroll
    for (int ky = 0; ky < 3; ++ky) {
#pragma unroll
      for (int kx = 0; kx < 3; ++kx) {
        float v = sIn[cin * 324 + (ty + ky) * 18 + tx + kx];
        const float* __restrict__ wr = w1t + (cin * 9 + ky * 3 + kx) * 32;
#pragma unroll
        for (int o = 0; o < 32; ++o) acc[o] = fmaf(v, wr[o], acc[o]);
      }
    }
  }
  // NHWC bf16 store: 64B per thread
  size_t ob = (((size_t)(n * 256 + ty0 + ty)) * 256 + tx0 + tx) * 32;
  ushort tmp[32];
#pragma unroll
  for (int o = 0; o < 32; ++o) tmp[o] = f2bf(fmaxf(acc[o], 0.f));
#pragma unroll
  for (int vv = 0; vv < 4; ++vv)
    *(u16x8*)&x1[ob + vv * 8] = *(u16x8*)&tmp[vv * 8];
}

// ---------------- conv2 (MFMA bf16 implicit GEMM) + fused conv3 ----------------
// block: 16x16 pixels, 4 waves; wave tile M=64 (4 rows x 16 px) x N=64
__global__ __launch_bounds__(256) void conv2_kernel(char* __restrict__ wsb,
                                                    const float* __restrict__ w3) {
  __shared__ ushort smem[256 * 68];  // 34816 B; [0,10368) doubles as input tile [18][18][32]
  const ushort* __restrict__ x1 = (const ushort*)(wsb + OFF_X1B);
  const short8* __restrict__ w2fv = (const short8*)(wsb + OFF_W2FB);
  const float* __restrict__ b2f = (const float*)(wsb + OFF_B2FB);
  float* aff = (float*)(wsb + OFF_AFFB);

  int blk = blockIdx.x;
  int n = blk >> 8;
  int t = blk & 255;
  int ty0 = (t >> 4) << 4;
  int tx0 = (t & 15) << 4;
  int tid = threadIdx.x;

  // ---- stage 18x18x32 bf16 input tile (16B chunks; zero halo) ----
  for (int e = tid; e < 1296; e += 256) {
    int y = e / 72;
    int rem = e - y * 72;
    int x = rem >> 2;
    int q = rem & 3;
    int gy = ty0 + y - 1, gx = tx0 + x - 1;
    u16x8 val = (u16x8)0;
    if (gy >= 0 && gy < HH && gx >= 0 && gx < WW)
      val = *(const u16x8*)&x1[(((size_t)(n * 256 + gy)) * 256 + gx) * 32 + q * 8];
    *(u16x8*)&smem[(y * 18 + x) * 32 + q * 8] = val;
  }
  __syncthreads();

  int lane = tid & 63;
  int wid = tid >> 6;
  int q = lane >> 4;
  int lx = lane & 15;

  f32x4 acc[4][4];
#pragma unroll
  for (int mt = 0; mt < 4; ++mt)
#pragma unroll
    for (int nt = 0; nt < 4; ++nt) acc[mt][nt] = (f32x4)0.f;

#pragma unroll
  for (int kk = 0; kk < 9; ++kk) {
    int ky = kk / 3, kx = kk - ky * 3;
    short8 a[4], b[4];
#pragma unroll
    for (int mt = 0; mt < 4; ++mt) {
      int row = wid * 4 + mt;
      a[mt] = *(const short8*)&smem[((row + ky) * 18 + lx + kx) * 32 + q * 8];
    }
#pragma unroll
    for (int nt = 0; nt < 4; ++nt) b[nt] = w2fv[(kk * 4 + nt) * 64 + lane];
#pragma unroll
    for (int mt = 0; mt < 4; ++mt)
#pragma unroll
      for (int nt = 0; nt < 4; ++nt)
        acc[mt][nt] = __builtin_amdgcn_mfma_f32_16x16x32_bf16(a[mt], b[nt], acc[mt][nt], 0, 0, 0);
  }

  // ---- epilogue: bias+ReLU, relayout to [pixel][ch] bf16 in LDS ----
  __syncthreads();  // everyone done reading input tile
#pragma unroll
  for (int nt = 0; nt < 4; ++nt) {
    float bias = b2f[nt * 16 + lx];
#pragma unroll
    for (int mt = 0; mt < 4; ++mt) {
      int row = wid * 4 + mt;
#pragma unroll
      for (int r = 0; r < 4; ++r) {
        int p = row * 16 + q * 4 + r;  // D-layout: row-in-tile = q*4+reg
        float v = fmaxf(acc[mt][nt][r] + bias, 0.f);
        smem[p * 68 + nt * 16 + lx] = f2bf(v);
      }
    }
  }
  __syncthreads();

  // ---- conv3 1x1 64->8 + ReLU, one pixel per thread ----
  int p = tid;
  float x2v[64];
#pragma unroll
  for (int cb = 0; cb < 8; ++cb) {
    u16x8 hv = *(const u16x8*)&smem[p * 68 + cb * 8];
#pragma unroll
    for (int jj = 0; jj < 8; ++jj) x2v[cb * 8 + jj] = bf2f(hv[jj]);
  }
  int py = ty0 + (p >> 4), px = tx0 + (p & 15);
  size_t obase = (size_t)n * 8 * HW + (size_t)py * WW + px;
#pragma unroll
  for (int k = 0; k < 8; ++k) {
    float s = 0.f;
#pragma unroll
    for (int c = 0; c < 64; ++c) s = fmaf(x2v[c], w3[k * 64 + c], s);
    aff[obase + (size_t)k * HW] = fmaxf(s, 0.f);
  }
}

// ---------------- final: 8-neighbor softmax-gated propagation ----------------
__global__ __launch_bounds__(256) void final_kernel(const float* __restrict__ disp,
                                                    const char* __restrict__ wsb,
                                                    float* __restrict__ out) {
  int gid = blockIdx.x * 256 + threadIdx.x;
  int n = gid / HW;
  int r = gid - n * HW;
  int i = r / WW;
  int j = r - i * WW;
  const float* aff = (const float*)(wsb + OFF_AFFB);
  const int dy[8] = {1, 1, 1, 0, 0, -1, -1, -1};
  const int dx[8] = {1, 0, -1, 1, -1, 1, 0, -1};
  float g[8], dv[8];
#pragma unroll
  for (int k = 0; k < 8; ++k) {
    int y = i + dy[k], x = j + dx[k];
    bool ok = (y >= 0 && y < HH && x >= 0 && x < WW);
    g[k] = ok ? aff[(size_t)(n * 8 + k) * HW + y * WW + x] : 0.f;
    dv[k] = ok ? disp[n * HW + y * WW + x] : 0.f;
  }
  float m = g[0];
#pragma unroll
  for (int k = 1; k < 8; ++k) m = fmaxf(m, g[k]);
  float se = 0.f, sed = 0.f;
#pragma unroll
  for (int k = 0; k < 8; ++k) {
    float e = __expf(g[k] - m);
    se += e;
    sed += e * dv[k];
  }
  float dc = disp[n * HW + i * WW + j];
  out[gid] = 0.3f * (sed / se) + 0.7f * dc;
}

extern "C" void kernel_launch(void* const* d_in, const int* in_sizes, int n_in,
                              void* d_out, int out_size, void* d_ws, size_t ws_size,
                              hipStream_t stream) {
  const float* normal = (const float*)d_in[0];
  const float* left   = (const float*)d_in[1];
  const float* right  = (const float*)d_in[2];
  const float* disp   = (const float*)d_in[3];
  const float* w1 = (const float*)d_in[4];
  const float* g1 = (const float*)d_in[5];
  const float* b1 = (const float*)d_in[6];
  const float* m1 = (const float*)d_in[7];
  const float* v1 = (const float*)d_in[8];
  const float* w2 = (const float*)d_in[9];
  const float* g2 = (const float*)d_in[10];
  const float* b2 = (const float*)d_in[11];
  const float* m2 = (const float*)d_in[12];
  const float* v2 = (const float*)d_in[13];
  const float* w3 = (const float*)d_in[14];
  char* wsb  = (char*)d_ws;
  float* out = (float*)d_out;

  hipLaunchKernelGGL(prep_weights, dim3(86), dim3(256), 0, stream,
                     w1, g1, b1, m1, v1, w2, g2, b2, m2, v2, wsb);
  hipLaunchKernelGGL(build_feats, dim3(2048), dim3(256), 0, stream,
                     normal, left, right, disp, wsb);
  hipLaunchKernelGGL(conv1_kernel, dim3(2048), dim3(256), 0, stream, wsb);
  hipLaunchKernelGGL(conv2_kernel, dim3(2048), dim3(256), 0, stream, wsb, w3);
  hipLaunchKernelGGL(final_kernel, dim3(2048), dim3(256), 0, stream, disp, wsb, out);
}

// Round 3
// 181.110 us; speedup vs baseline: 2.6119x; 1.2213x over previous
//
#include <hip/hip_runtime.h>
#include <math.h>

#define NB 8
#define HH 256
#define WW 256
#define HW (HH*WW)

// ---- workspace layout (BYTE offsets) ----
#define OFF_FEATS 0UL                 // [8][256][256][16] bf16  (16777216 B) ch: 0-2 normal,3-5 cl,6-8 cr,9-11 err,12-15 zero
#define OFF_X1B   16777216UL          // [8][256][256][32] bf16  (33554432 B)
#define OFF_AFFB  50331648UL          // [8][8][256][256]  fp32  (16777216 B)
#define OFF_W1FB  67108864UL          // [6][2][64][8] bf16 A-fragment order (12288 B)
#define OFF_B1FB  67121152UL          // [32] fp32
#define OFF_W2FB  67121280UL          // [18432] bf16, MFMA B-fragment order
#define OFF_B2FB  67158144UL          // [64] fp32

typedef short  short8 __attribute__((ext_vector_type(8)));
typedef ushort u16x8  __attribute__((ext_vector_type(8)));
typedef ushort u16x4  __attribute__((ext_vector_type(4)));
typedef float  f32x4  __attribute__((ext_vector_type(4)));

__device__ __forceinline__ ushort f2bf(float x) {
  uint u = __float_as_uint(x);
  return (ushort)((u + 0x7FFFu + ((u >> 16) & 1u)) >> 16);
}
__device__ __forceinline__ float bf2f(ushort h) {
  uint u = ((uint)h) << 16;
  return __uint_as_float(u);
}

// ---------------- prep: fold BN; w1 -> bf16 A-frag order; w2 -> bf16 B-frag order ----------------
__global__ __launch_bounds__(256) void prep_weights(
    const float* __restrict__ w1, const float* __restrict__ g1,
    const float* __restrict__ b1, const float* __restrict__ m1,
    const float* __restrict__ v1,
    const float* __restrict__ w2, const float* __restrict__ g2,
    const float* __restrict__ b2, const float* __restrict__ m2,
    const float* __restrict__ v2,
    char* __restrict__ wsb) {
  int idx = blockIdx.x * 256 + threadIdx.x;
  ushort* w1f = (ushort*)(wsb + OFF_W1FB);
  float* b1f  = (float*)(wsb + OFF_B1FB);
  ushort* w2f = (ushort*)(wsb + OFF_W2FB);
  float* b2f  = (float*)(wsb + OFF_B2FB);
  if (idx < 6144) {
    // idx = ((s*2+mt)*64 + lane)*8 + jj ; s = ky*2+t
    int jj = idx & 7;
    int lane = (idx >> 3) & 63;
    int mt = (idx >> 9) & 1;
    int s = idx >> 10;
    int ky = s >> 1, t = s & 1;
    int q = lane >> 4, lx = lane & 15;
    int k = q * 8 + jj;
    int dcol = k >> 4, ch = k & 15;
    int kx = t * 2 + dcol;
    int out = mt * 16 + lx;
    float inv = g1[out] / sqrtf(v1[out] + 1e-5f);
    float val = (ch < 12 && kx < 3) ? w1[((out * 12 + ch) * 3 + ky) * 3 + kx] * inv : 0.f;
    w1f[idx] = f2bf(val);
  }
  int j = idx - 6144;
  if (j >= 0 && j < 18432) {
    int kk   = j >> 11;          // 0..8
    int nt   = (j >> 9) & 3;     // 0..3
    int lane = (j >> 3) & 63;    // 0..63
    int jj   = j & 7;            // 0..7
    int q  = lane >> 4, lx = lane & 15;
    int cin = q * 8 + jj;        // 0..31
    int out = nt * 16 + lx;      // 0..63
    float inv = g2[out] / sqrtf(v2[out] + 1e-5f);
    w2f[j] = f2bf(w2[(out * 32 + cin) * 9 + kk] * inv);
    if (kk == 0 && q == 0 && jj == 0) b2f[out] = b2[out] - m2[out] * inv;
  }
  int k2 = idx - 24576;
  if (k2 >= 0 && k2 < 32) {
    float inv = g1[k2] / sqrtf(v1[k2] + 1e-5f);
    b1f[k2] = b1[k2] - m1[k2] * inv;
  }
}

// ---------------- feats: resize(2x box) + lr-warp error + concat -> NHWC16 bf16 ----------------
__device__ __forceinline__ float avg4(const float* __restrict__ img, int n, int c,
                                      int i2, int x) {
  const float* p = img + ((size_t)(n * 3 + c) * 512 + i2) * 512 + 2 * x;
  float2 a = *(const float2*)p;
  float2 b = *(const float2*)(p + 512);
  return 0.25f * (a.x + a.y + b.x + b.y);
}

__global__ __launch_bounds__(256) void build_feats(
    const float* __restrict__ normal, const float* __restrict__ left,
    const float* __restrict__ right, const float* __restrict__ disp,
    char* __restrict__ wsb) {
  int gid = blockIdx.x * 256 + threadIdx.x;
  int n = gid / HW;
  int r = gid - n * HW;
  int i = r / WW;
  int j = r - i * WW;
  ushort* feats = (ushort*)(wsb + OFF_FEATS);
  ushort tmp[16];
  int i2 = 2 * i;
#pragma unroll
  for (int c = 0; c < 3; ++c)
    tmp[c] = f2bf(normal[(size_t)(n * 3 + c) * HW + i * WW + j]);
  float cl[3];
#pragma unroll
  for (int c = 0; c < 3; ++c) {
    cl[c] = avg4(left, n, c, i2, j);
    float cr = avg4(right, n, c, i2, j);
    tmp[3 + c] = f2bf(cl[c]);
    tmp[6 + c] = f2bf(cr);
  }
  float d = disp[n * HW + i * WW + j];
  float xs = (float)j - d;
  float x0f = floorf(xs);
  float fr = xs - x0f;
  int x0 = (int)x0f;
  int x1 = x0 + 1;
  float v0 = (x0 >= 0 && x0 < WW) ? 1.f : 0.f;
  float v1 = (x1 >= 0 && x1 < WW) ? 1.f : 0.f;
  int x0c = min(max(x0, 0), WW - 1);
  int x1c = min(max(x1, 0), WW - 1);
#pragma unroll
  for (int c = 0; c < 3; ++c) {
    float gg0 = avg4(right, n, c, i2, x0c) * v0;
    float gg1 = avg4(right, n, c, i2, x1c) * v1;
    float warped = gg0 * (1.f - fr) + gg1 * fr;
    tmp[9 + c] = f2bf(fabsf(cl[c] - warped));
  }
#pragma unroll
  for (int c = 12; c < 16; ++c) tmp[c] = 0;
  size_t ob = ((size_t)gid) * 16;
  *(u16x8*)&feats[ob] = *(u16x8*)&tmp[0];
  *(u16x8*)&feats[ob + 8] = *(u16x8*)&tmp[8];
}

// ---------------- conv1 (MFMA bf16): 3x3 12(->16)->32 + BN + ReLU -> NHWC32 bf16 ----------------
// A = weights (m=outch), B = pixels (n=pixel col). K=32 = 2 adjacent px x 16ch.
__global__ __launch_bounds__(256) void conv1_kernel(char* __restrict__ wsb) {
  __shared__ ushort tile[688 * 8];  // 684 16B chunks + swizzle headroom
  const ushort* __restrict__ feats = (const ushort*)(wsb + OFF_FEATS);
  const short8* __restrict__ w1fv = (const short8*)(wsb + OFF_W1FB);
  const float* __restrict__ b1f = (const float*)(wsb + OFF_B1FB);
  ushort* x1 = (ushort*)(wsb + OFF_X1B);
  int blk = blockIdx.x;
  int n = blk >> 8;
  int t = blk & 255;
  int ty0 = (t >> 4) << 4;
  int tx0 = (t & 15) << 4;
  int tid = threadIdx.x;
  // stage 18 rows x 19 cols x 16ch bf16, chunk-XOR-swizzled
  for (int e = tid; e < 684; e += 256) {
    int row = e / 38;
    int rem = e - row * 38;
    int col = rem >> 1;
    int cc = rem & 1;
    int gy = ty0 + row - 1, gx = tx0 + col - 1;
    u16x8 v = (u16x8)0;
    if (gy >= 0 && gy < HH && gx >= 0 && gx < WW)
      v = *(const u16x8*)&feats[(((size_t)(n * 256 + gy)) * 256 + gx) * 16 + cc * 8];
    int slot = e ^ ((e >> 3) & 7);
    *(u16x8*)&tile[slot * 8] = v;
  }
  __syncthreads();
  int lane = tid & 63;
  int wid = tid >> 6;
  int q = lane >> 4;
  int lx = lane & 15;
  // preload 12 weight A-fragments (L2-resident)
  short8 aw[2][6];
#pragma unroll
  for (int s = 0; s < 6; ++s)
#pragma unroll
    for (int mt = 0; mt < 2; ++mt) aw[mt][s] = w1fv[(s * 2 + mt) * 64 + lane];
  f32x4 acc[4][2];
#pragma unroll
  for (int rowt = 0; rowt < 4; ++rowt)
#pragma unroll
    for (int mt = 0; mt < 2; ++mt) acc[rowt][mt] = (f32x4)0.f;
#pragma unroll
  for (int s = 0; s < 6; ++s) {
    int ky = s >> 1;
    int kxs = (s & 1) * 2;
#pragma unroll
    for (int rowt = 0; rowt < 4; ++rowt) {
      int prow = wid * 4 + rowt + ky;
      int G = (prow * 19 + lx + kxs + (q >> 1)) * 2 + (q & 1);
      int slot = G ^ ((G >> 3) & 7);
      short8 b = *(const short8*)&tile[slot * 8];
      acc[rowt][0] = __builtin_amdgcn_mfma_f32_16x16x32_bf16(aw[0][s], b, acc[rowt][0], 0, 0, 0);
      acc[rowt][1] = __builtin_amdgcn_mfma_f32_16x16x32_bf16(aw[1][s], b, acc[rowt][1], 0, 0, 0);
    }
  }
  // epilogue: D row = out-ch (q*4+r), col = pixel lx -> ushort4 (4 consecutive ch) stores
#pragma unroll
  for (int rowt = 0; rowt < 4; ++rowt) {
    int gy = ty0 + wid * 4 + rowt;
    int gx = tx0 + lx;
    size_t pb = (((size_t)(n * 256 + gy)) * 256 + gx) * 32;
#pragma unroll
    for (int mt = 0; mt < 2; ++mt) {
      u16x4 pack;
#pragma unroll
      for (int r = 0; r < 4; ++r) {
        int ch = mt * 16 + q * 4 + r;
        pack[r] = f2bf(fmaxf(acc[rowt][mt][r] + b1f[ch], 0.f));
      }
      *(u16x4*)&x1[pb + mt * 16 + q * 4] = pack;
    }
  }
}

// ---------------- conv2 (MFMA bf16) + fused conv3; LDS pixel stride padded 32->36 ----------------
__global__ __launch_bounds__(256) void conv2_kernel(char* __restrict__ wsb,
                                                    const float* __restrict__ w3) {
  __shared__ ushort smem[256 * 68];  // 34816 B; input tile uses [0, 18*18*36) ushorts
  const ushort* __restrict__ x1 = (const ushort*)(wsb + OFF_X1B);
  const short8* __restrict__ w2fv = (const short8*)(wsb + OFF_W2FB);
  const float* __restrict__ b2f = (const float*)(wsb + OFF_B2FB);
  float* aff = (float*)(wsb + OFF_AFFB);

  int blk = blockIdx.x;
  int n = blk >> 8;
  int t = blk & 255;
  int ty0 = (t >> 4) << 4;
  int tx0 = (t & 15) << 4;
  int tid = threadIdx.x;

  // stage 18x18x32 bf16, pixel stride 36 ushorts
  for (int e = tid; e < 1296; e += 256) {
    int p = e >> 2;
    int c = e & 3;
    int y = p / 18;
    int x = p - y * 18;
    int gy = ty0 + y - 1, gx = tx0 + x - 1;
    u16x8 val = (u16x8)0;
    if (gy >= 0 && gy < HH && gx >= 0 && gx < WW)
      val = *(const u16x8*)&x1[(((size_t)(n * 256 + gy)) * 256 + gx) * 32 + c * 8];
    *(u16x8*)&smem[p * 36 + c * 8] = val;
  }
  __syncthreads();

  int lane = tid & 63;
  int wid = tid >> 6;
  int q = lane >> 4;
  int lx = lane & 15;

  f32x4 acc[4][4];
#pragma unroll
  for (int mt = 0; mt < 4; ++mt)
#pragma unroll
    for (int nt = 0; nt < 4; ++nt) acc[mt][nt] = (f32x4)0.f;

#pragma unroll
  for (int kk = 0; kk < 9; ++kk) {
    int ky = kk / 3, kx = kk - ky * 3;
    short8 a[4], b[4];
#pragma unroll
    for (int mt = 0; mt < 4; ++mt) {
      int row = wid * 4 + mt;
      a[mt] = *(const short8*)&smem[((row + ky) * 18 + lx + kx) * 36 + q * 8];
    }
#pragma unroll
    for (int nt = 0; nt < 4; ++nt) b[nt] = w2fv[(kk * 4 + nt) * 64 + lane];
#pragma unroll
    for (int mt = 0; mt < 4; ++mt)
#pragma unroll
      for (int nt = 0; nt < 4; ++nt)
        acc[mt][nt] = __builtin_amdgcn_mfma_f32_16x16x32_bf16(a[mt], b[nt], acc[mt][nt], 0, 0, 0);
  }

  // epilogue: bias+ReLU, relayout to [pixel][ch] bf16 in LDS
  __syncthreads();
#pragma unroll
  for (int nt = 0; nt < 4; ++nt) {
    float bias = b2f[nt * 16 + lx];
#pragma unroll
    for (int mt = 0; mt < 4; ++mt) {
      int row = wid * 4 + mt;
#pragma unroll
      for (int r = 0; r < 4; ++r) {
        int p = row * 16 + q * 4 + r;
        float v = fmaxf(acc[mt][nt][r] + bias, 0.f);
        smem[p * 68 + nt * 16 + lx] = f2bf(v);
      }
    }
  }
  __syncthreads();

  // conv3 1x1 64->8 + ReLU, one pixel per thread
  int p = tid;
  float x2v[64];
#pragma unroll
  for (int cb = 0; cb < 8; ++cb) {
    u16x8 hv = *(const u16x8*)&smem[p * 68 + cb * 8];
#pragma unroll
    for (int jj = 0; jj < 8; ++jj) x2v[cb * 8 + jj] = bf2f(hv[jj]);
  }
  int py = ty0 + (p >> 4), px = tx0 + (p & 15);
  size_t obase = (size_t)n * 8 * HW + (size_t)py * WW + px;
#pragma unroll
  for (int k = 0; k < 8; ++k) {
    float s = 0.f;
#pragma unroll
    for (int c = 0; c < 64; ++c) s = fmaf(x2v[c], w3[k * 64 + c], s);
    aff[obase + (size_t)k * HW] = fmaxf(s, 0.f);
  }
}

// ---------------- final: 8-neighbor softmax-gated propagation ----------------
__global__ __launch_bounds__(256) void final_kernel(const float* __restrict__ disp,
                                                    const char* __restrict__ wsb,
                                                    float* __restrict__ out) {
  int gid = blockIdx.x * 256 + threadIdx.x;
  int n = gid / HW;
  int r = gid - n * HW;
  int i = r / WW;
  int j = r - i * WW;
  const float* aff = (const float*)(wsb + OFF_AFFB);
  const int dy[8] = {1, 1, 1, 0, 0, -1, -1, -1};
  const int dx[8] = {1, 0, -1, 1, -1, 1, 0, -1};
  float g[8], dv[8];
#pragma unroll
  for (int k = 0; k < 8; ++k) {
    int y = i + dy[k], x = j + dx[k];
    bool ok = (y >= 0 && y < HH && x >= 0 && x < WW);
    g[k] = ok ? aff[(size_t)(n * 8 + k) * HW + y * WW + x] : 0.f;
    dv[k] = ok ? disp[n * HW + y * WW + x] : 0.f;
  }
  float m = g[0];
#pragma unroll
  for (int k = 1; k < 8; ++k) m = fmaxf(m, g[k]);
  float se = 0.f, sed = 0.f;
#pragma unroll
  for (int k = 0; k < 8; ++k) {
    float e = __expf(g[k] - m);
    se += e;
    sed += e * dv[k];
  }
  float dc = disp[n * HW + i * WW + j];
  out[gid] = 0.3f * (sed / se) + 0.7f * dc;
}

extern "C" void kernel_launch(void* const* d_in, const int* in_sizes, int n_in,
                              void* d_out, int out_size, void* d_ws, size_t ws_size,
                              hipStream_t stream) {
  const float* normal = (const float*)d_in[0];
  const float* left   = (const float*)d_in[1];
  const float* right  = (const float*)d_in[2];
  const float* disp   = (const float*)d_in[3];
  const float* w1 = (const float*)d_in[4];
  const float* g1 = (const float*)d_in[5];
  const float* b1 = (const float*)d_in[6];
  const float* m1 = (const float*)d_in[7];
  const float* v1 = (const float*)d_in[8];
  const float* w2 = (const float*)d_in[9];
  const float* g2 = (const float*)d_in[10];
  const float* b2 = (const float*)d_in[11];
  const float* m2 = (const float*)d_in[12];
  const float* v2 = (const float*)d_in[13];
  const float* w3 = (const float*)d_in[14];
  char* wsb  = (char*)d_ws;
  float* out = (float*)d_out;

  hipLaunchKernelGGL(prep_weights, dim3(97), dim3(256), 0, stream,
                     w1, g1, b1, m1, v1, w2, g2, b2, m2, v2, wsb);
  hipLaunchKernelGGL(build_feats, dim3(2048), dim3(256), 0, stream,
                     normal, left, right, disp, wsb);
  hipLaunchKernelGGL(conv1_kernel, dim3(2048), dim3(256), 0, stream, wsb);
  hipLaunchKernelGGL(conv2_kernel, dim3(2048), dim3(256), 0, stream, wsb, w3);
  hipLaunchKernelGGL(final_kernel, dim3(2048), dim3(256), 0, stream, disp, wsb, out);
}

// Round 5
// 167.323 us; speedup vs baseline: 2.8271x; 1.0824x over previous
//
#include <hip/hip_runtime.h>
#include <math.h>

#define NB 8
#define HH 256
#define WW 256
#define HW (HH*WW)

// ---- workspace layout (BYTE offsets) ----
#define OFF_FEATS 0UL                 // [8][256][256][16] bf16 (16777216 B)
#define OFF_X1B   16777216UL          // [8][256][256][32] bf16 (33554432 B)
#define OFF_AFFB  50331648UL          // [8][8][256][256]  bf16 (8388608 B)
#define OFF_W1FB  58720256UL          // [6][2][64][8] bf16 A-frag order (12288 B)
#define OFF_B1FB  58732544UL          // [32] fp32
#define OFF_W2FB  58732672UL          // [9][4][64][8] bf16 B-frag order (36864 B)
#define OFF_B2FB  58769536UL          // [64] fp32
#define OFF_W3FB  58769792UL          // [2][64][8] bf16 B-frag order (2048 B)

typedef short  short8 __attribute__((ext_vector_type(8)));
typedef ushort u16x8  __attribute__((ext_vector_type(8)));
typedef ushort u16x4  __attribute__((ext_vector_type(4)));
typedef float  f32x4  __attribute__((ext_vector_type(4)));

__device__ __forceinline__ ushort f2bf(float x) {
  uint u = __float_as_uint(x);
  return (ushort)((u + 0x7FFFu + ((u >> 16) & 1u)) >> 16);
}
__device__ __forceinline__ float bf2f(ushort h) {
  uint u = ((uint)h) << 16;
  return __uint_as_float(u);
}

// ---------------- feats (blocks < 2048) + weight prep (blocks >= 2048) ----------------
__device__ __forceinline__ float avg4(const float* __restrict__ img, int n, int c,
                                      int i2, int x) {
  const float* p = img + ((size_t)(n * 3 + c) * 512 + i2) * 512 + 2 * x;
  float2 a = *(const float2*)p;
  float2 b = *(const float2*)(p + 512);
  return 0.25f * (a.x + a.y + b.x + b.y);
}

__global__ __launch_bounds__(256) void build_feats(
    const float* __restrict__ normal, const float* __restrict__ left,
    const float* __restrict__ right, const float* __restrict__ disp,
    const float* __restrict__ w1, const float* __restrict__ g1,
    const float* __restrict__ b1, const float* __restrict__ m1,
    const float* __restrict__ v1,
    const float* __restrict__ w2, const float* __restrict__ g2,
    const float* __restrict__ b2, const float* __restrict__ m2,
    const float* __restrict__ v2, const float* __restrict__ w3,
    char* __restrict__ wsb) {
  if (blockIdx.x >= 2048) {
    int idx = (blockIdx.x - 2048) * 256 + threadIdx.x;
    ushort* w1f = (ushort*)(wsb + OFF_W1FB);
    float* b1f  = (float*)(wsb + OFF_B1FB);
    ushort* w2f = (ushort*)(wsb + OFF_W2FB);
    float* b2f  = (float*)(wsb + OFF_B2FB);
    ushort* w3f = (ushort*)(wsb + OFF_W3FB);
    if (idx < 6144) {
      int jj = idx & 7;
      int lane = (idx >> 3) & 63;
      int mt = (idx >> 9) & 1;
      int s = idx >> 10;
      int ky = s >> 1, t = s & 1;
      int q = lane >> 4, lx = lane & 15;
      int k = q * 8 + jj;
      int dcol = k >> 4, ch = k & 15;
      int kx = t * 2 + dcol;
      int out = mt * 16 + lx;
      float inv = g1[out] / sqrtf(v1[out] + 1e-5f);
      float val = (ch < 12 && kx < 3) ? w1[((out * 12 + ch) * 3 + ky) * 3 + kx] * inv : 0.f;
      w1f[idx] = f2bf(val);
    }
    int j = idx - 6144;
    if (j >= 0 && j < 18432) {
      int kk   = j >> 11;
      int nt   = (j >> 9) & 3;
      int lane = (j >> 3) & 63;
      int jj   = j & 7;
      int q  = lane >> 4, lx = lane & 15;
      int cin = q * 8 + jj;
      int out = nt * 16 + lx;
      float inv = g2[out] / sqrtf(v2[out] + 1e-5f);
      w2f[j] = f2bf(w2[(out * 32 + cin) * 9 + kk] * inv);
      if (kk == 0 && q == 0 && jj == 0) b2f[out] = b2[out] - m2[out] * inv;
    }
    int k2 = idx - 24576;
    if (k2 >= 0 && k2 < 32) {
      float inv = g1[k2] / sqrtf(v1[k2] + 1e-5f);
      b1f[k2] = b1[k2] - m1[k2] * inv;
    }
    int k3 = idx - 24608;
    if (k3 >= 0 && k3 < 1024) {
      int jj = k3 & 7;
      int lane = (k3 >> 3) & 63;
      int slice = k3 >> 9;
      int q = lane >> 4, lx = lane & 15;
      int ch = slice * 32 + q * 8 + jj;
      w3f[k3] = (lx < 8) ? f2bf(w3[lx * 64 + ch]) : (ushort)0;
    }
    return;
  }
  int gid = blockIdx.x * 256 + threadIdx.x;
  int n = gid / HW;
  int r = gid - n * HW;
  int i = r / WW;
  int j = r - i * WW;
  ushort* feats = (ushort*)(wsb + OFF_FEATS);
  ushort tmp[16];
  int i2 = 2 * i;
#pragma unroll
  for (int c = 0; c < 3; ++c)
    tmp[c] = f2bf(normal[(size_t)(n * 3 + c) * HW + i * WW + j]);
  float cl[3];
#pragma unroll
  for (int c = 0; c < 3; ++c) {
    cl[c] = avg4(left, n, c, i2, j);
    float cr = avg4(right, n, c, i2, j);
    tmp[3 + c] = f2bf(cl[c]);
    tmp[6 + c] = f2bf(cr);
  }
  float d = disp[n * HW + i * WW + j];
  float xs = (float)j - d;
  float x0f = floorf(xs);
  float fr = xs - x0f;
  int ix0 = (int)x0f;
  int ix1 = ix0 + 1;
  float vm0 = (ix0 >= 0 && ix0 < WW) ? 1.f : 0.f;
  float vm1 = (ix1 >= 0 && ix1 < WW) ? 1.f : 0.f;
  int x0c = min(max(ix0, 0), WW - 1);
  int x1c = min(max(ix1, 0), WW - 1);
#pragma unroll
  for (int c = 0; c < 3; ++c) {
    float gg0 = avg4(right, n, c, i2, x0c) * vm0;
    float gg1 = avg4(right, n, c, i2, x1c) * vm1;
    float warped = gg0 * (1.f - fr) + gg1 * fr;
    tmp[9 + c] = f2bf(fabsf(cl[c] - warped));
  }
#pragma unroll
  for (int c = 12; c < 16; ++c) tmp[c] = 0;
  size_t ob = ((size_t)gid) * 16;
  *(u16x8*)&feats[ob] = *(u16x8*)&tmp[0];
  *(u16x8*)&feats[ob + 8] = *(u16x8*)&tmp[8];
}

// ---------------- conv1 (MFMA bf16): 3x3 12(->16)->32 -> NHWC32 bf16 ----------------
__global__ __launch_bounds__(256) void conv1_kernel(char* __restrict__ wsb) {
  __shared__ ushort tile[688 * 8];
  const ushort* __restrict__ feats = (const ushort*)(wsb + OFF_FEATS);
  const short8* __restrict__ w1fv = (const short8*)(wsb + OFF_W1FB);
  const float* __restrict__ b1f = (const float*)(wsb + OFF_B1FB);
  ushort* x1 = (ushort*)(wsb + OFF_X1B);
  int blk = blockIdx.x;
  int n = blk >> 8;
  int t = blk & 255;
  int ty0 = (t >> 4) << 4;
  int tx0 = (t & 15) << 4;
  int tid = threadIdx.x;
  int lane = tid & 63;
  int wid = tid >> 6;
  int q = lane >> 4;
  int lx = lane & 15;
  // preload 12 weight A-fragments early (global, L2-hot)
  short8 aw[2][6];
#pragma unroll
  for (int s = 0; s < 6; ++s)
#pragma unroll
    for (int mt = 0; mt < 2; ++mt) aw[mt][s] = w1fv[(s * 2 + mt) * 64 + lane];
  // stage 18x19x16ch bf16 tile, chunk-XOR-swizzled
  for (int e = tid; e < 684; e += 256) {
    int row = e / 38;
    int rem = e - row * 38;
    int col = rem >> 1;
    int cc = rem & 1;
    int gy = ty0 + row - 1, gx = tx0 + col - 1;
    u16x8 v = (u16x8)0;
    if (gy >= 0 && gy < HH && gx >= 0 && gx < WW)
      v = *(const u16x8*)&feats[(((size_t)(n * 256 + gy)) * 256 + gx) * 16 + cc * 8];
    int slot = e ^ ((e >> 3) & 7);
    *(u16x8*)&tile[slot * 8] = v;
  }
  __syncthreads();
  // 12 distinct B fragments (pixel-pairs), reused across (rowt,ky)
  short8 bfrag[6][2];
#pragma unroll
  for (int dr = 0; dr < 6; ++dr)
#pragma unroll
    for (int tt = 0; tt < 2; ++tt) {
      int prow = wid * 4 + dr;
      int G = (prow * 19 + lx + tt * 2 + (q >> 1)) * 2 + (q & 1);
      int slot = G ^ ((G >> 3) & 7);
      bfrag[dr][tt] = *(const short8*)&tile[slot * 8];
    }
  f32x4 acc[4][2];
#pragma unroll
  for (int rowt = 0; rowt < 4; ++rowt)
#pragma unroll
    for (int mt = 0; mt < 2; ++mt) acc[rowt][mt] = (f32x4)0.f;
#pragma unroll
  for (int s = 0; s < 6; ++s) {
    int ky = s >> 1;
    int tt = s & 1;
#pragma unroll
    for (int rowt = 0; rowt < 4; ++rowt) {
      short8 b = bfrag[rowt + ky][tt];
      acc[rowt][0] = __builtin_amdgcn_mfma_f32_16x16x32_bf16(aw[0][s], b, acc[rowt][0], 0, 0, 0);
      acc[rowt][1] = __builtin_amdgcn_mfma_f32_16x16x32_bf16(aw[1][s], b, acc[rowt][1], 0, 0, 0);
    }
  }
#pragma unroll
  for (int rowt = 0; rowt < 4; ++rowt) {
    int gy = ty0 + wid * 4 + rowt;
    int gx = tx0 + lx;
    size_t pb = (((size_t)(n * 256 + gy)) * 256 + gx) * 32;
#pragma unroll
    for (int mt = 0; mt < 2; ++mt) {
      u16x4 pack;
#pragma unroll
      for (int r = 0; r < 4; ++r) {
        int ch = mt * 16 + q * 4 + r;
        pack[r] = f2bf(fmaxf(acc[rowt][mt][r] + b1f[ch], 0.f));
      }
      *(u16x4*)&x1[pb + mt * 16 + q * 4] = pack;
    }
  }
}

// ---------------- conv2 (MFMA) + conv3 (MFMA) ----------------
__global__ __launch_bounds__(256) void conv2_kernel(char* __restrict__ wsb) {
  __shared__ ushort smem[256 * 68];  // 34816 B
  const ushort* __restrict__ x1 = (const ushort*)(wsb + OFF_X1B);
  const short8* __restrict__ w2fv = (const short8*)(wsb + OFF_W2FB);
  const float* __restrict__ b2f = (const float*)(wsb + OFF_B2FB);
  const short8* __restrict__ w3fv = (const short8*)(wsb + OFF_W3FB);
  ushort* aff = (ushort*)(wsb + OFF_AFFB);

  int blk = blockIdx.x;
  int n = blk >> 8;
  int t = blk & 255;
  int ty0 = (t >> 4) << 4;
  int tx0 = (t & 15) << 4;
  int tid = threadIdx.x;
  int lane = tid & 63;
  int wid = tid >> 6;
  int q = lane >> 4;
  int lx = lane & 15;

  // preload conv3 B-fragments early
  short8 bw3[2];
  bw3[0] = w3fv[lane];
  bw3[1] = w3fv[64 + lane];

  // stage 18x18x32 bf16, pixel stride 36 ushorts
  for (int e = tid; e < 1296; e += 256) {
    int p = e >> 2;
    int c = e & 3;
    int y = p / 18;
    int x = p - y * 18;
    int gy = ty0 + y - 1, gx = tx0 + x - 1;
    u16x8 val = (u16x8)0;
    if (gy >= 0 && gy < HH && gx >= 0 && gx < WW)
      val = *(const u16x8*)&x1[(((size_t)(n * 256 + gy)) * 256 + gx) * 32 + c * 8];
    *(u16x8*)&smem[p * 36 + c * 8] = val;
  }
  __syncthreads();

  f32x4 acc[4][4];
#pragma unroll
  for (int mt = 0; mt < 4; ++mt)
#pragma unroll
    for (int nt = 0; nt < 4; ++nt) acc[mt][nt] = (f32x4)0.f;

#pragma unroll
  for (int kk = 0; kk < 9; ++kk) {
    int ky = kk / 3, kx = kk - ky * 3;
    short8 a[4], b[4];
#pragma unroll
    for (int mt = 0; mt < 4; ++mt) {
      int row = wid * 4 + mt;
      a[mt] = *(const short8*)&smem[((row + ky) * 18 + lx + kx) * 36 + q * 8];
    }
#pragma unroll
    for (int nt = 0; nt < 4; ++nt) b[nt] = w2fv[(kk * 4 + nt) * 64 + lane];
#pragma unroll
    for (int mt = 0; mt < 4; ++mt)
#pragma unroll
      for (int nt = 0; nt < 4; ++nt)
        acc[mt][nt] = __builtin_amdgcn_mfma_f32_16x16x32_bf16(a[mt], b[nt], acc[mt][nt], 0, 0, 0);
  }

  // relayout D -> [pixel][ch] bf16 in LDS (stride 68)
  __syncthreads();
#pragma unroll
  for (int nt = 0; nt < 4; ++nt) {
    float bias = b2f[nt * 16 + lx];
#pragma unroll
    for (int mt = 0; mt < 4; ++mt) {
      int row = wid * 4 + mt;
#pragma unroll
      for (int r = 0; r < 4; ++r) {
        int p = row * 16 + q * 4 + r;
        float v = fmaxf(acc[mt][nt][r] + bias, 0.f);
        smem[p * 68 + nt * 16 + lx] = f2bf(v);
      }
    }
  }
  __syncthreads();

  // conv3 1x1 64->8 via MFMA: A = pixels (m=px, k=ch), B = w3
  f32x4 acc3[4];
#pragma unroll
  for (int mt = 0; mt < 4; ++mt) acc3[mt] = (f32x4)0.f;
#pragma unroll
  for (int mt = 0; mt < 4; ++mt) {
    int p = wid * 64 + mt * 16 + lx;
#pragma unroll
    for (int s = 0; s < 2; ++s) {
      short8 a3 = *(const short8*)&smem[p * 68 + s * 32 + q * 8];
      acc3[mt] = __builtin_amdgcn_mfma_f32_16x16x32_bf16(a3, bw3[s], acc3[mt], 0, 0, 0);
    }
  }
  // D: col = lane&15 = out-k (valid <8), row = q*4+r = pixel-in-16 -> 4 consecutive px
  if (lx < 8) {
#pragma unroll
    for (int mt = 0; mt < 4; ++mt) {
      int py = ty0 + wid * 4 + mt;
      int px = tx0 + q * 4;
      u16x4 pk;
#pragma unroll
      for (int r = 0; r < 4; ++r) pk[r] = f2bf(fmaxf(acc3[mt][r], 0.f));
      *(u16x4*)&aff[((size_t)(n * 8 + lx)) * HW + (size_t)py * WW + px] = pk;
    }
  }
}

// ---------------- final: 8-neighbor softmax-gated propagation ----------------
__global__ __launch_bounds__(256) void final_kernel(const float* __restrict__ disp,
                                                    const char* __restrict__ wsb,
                                                    float* __restrict__ out) {
  int gid = blockIdx.x * 256 + threadIdx.x;
  int n = gid / HW;
  int r = gid - n * HW;
  int i = r / WW;
  int j = r - i * WW;
  const ushort* aff = (const ushort*)(wsb + OFF_AFFB);
  const int dy[8] = {1, 1, 1, 0, 0, -1, -1, -1};
  const int dx[8] = {1, 0, -1, 1, -1, 1, 0, -1};
  float g[8], dv[8];
#pragma unroll
  for (int k = 0; k < 8; ++k) {
    int y = i + dy[k], x = j + dx[k];
    bool ok = (y >= 0 && y < HH && x >= 0 && x < WW);
    g[k] = ok ? bf2f(aff[(size_t)(n * 8 + k) * HW + y * WW + x]) : 0.f;
    dv[k] = ok ? disp[n * HW + y * WW + x] : 0.f;
  }
  float m = g[0];
#pragma unroll
  for (int k = 1; k < 8; ++k) m = fmaxf(m, g[k]);
  float se = 0.f, sed = 0.f;
#pragma unroll
  for (int k = 0; k < 8; ++k) {
    float e = __expf(g[k] - m);
    se += e;
    sed += e * dv[k];
  }
  float dc = disp[n * HW + i * WW + j];
  out[gid] = 0.3f * (sed / se) + 0.7f * dc;
}

extern "C" void kernel_launch(void* const* d_in, const int* in_sizes, int n_in,
                              void* d_out, int out_size, void* d_ws, size_t ws_size,
                              hipStream_t stream) {
  const float* normal = (const float*)d_in[0];
  const float* left   = (const float*)d_in[1];
  const float* right  = (const float*)d_in[2];
  const float* disp   = (const float*)d_in[3];
  const float* w1 = (const float*)d_in[4];
  const float* g1 = (const float*)d_in[5];
  const float* b1 = (const float*)d_in[6];
  const float* m1 = (const float*)d_in[7];
  const float* v1 = (const float*)d_in[8];
  const float* w2 = (const float*)d_in[9];
  const float* g2 = (const float*)d_in[10];
  const float* b2 = (const float*)d_in[11];
  const float* m2 = (const float*)d_in[12];
  const float* v2 = (const float*)d_in[13];
  const float* w3 = (const float*)d_in[14];
  char* wsb  = (char*)d_ws;
  float* out = (float*)d_out;

  hipLaunchKernelGGL(build_feats, dim3(2149), dim3(256), 0, stream,
                     normal, left, right, disp,
                     w1, g1, b1, m1, v1, w2, g2, b2, m2, v2, w3, wsb);
  hipLaunchKernelGGL(conv1_kernel, dim3(2048), dim3(256), 0, stream, wsb);
  hipLaunchKernelGGL(conv2_kernel, dim3(2048), dim3(256), 0, stream, wsb);
  hipLaunchKernelGGL(final_kernel, dim3(2048), dim3(256), 0, stream, disp, wsb, out);
}

// Round 6
// 166.507 us; speedup vs baseline: 2.8410x; 1.0049x over previous
//
#include <hip/hip_runtime.h>
#include <math.h>

#define NB 8
#define HH 256
#define WW 256
#define HW (HH*WW)

// ---- workspace layout (BYTE offsets) ----
#define OFF_FEATS 0UL                 // [8][256][256][16] bf16 (16777216 B)
#define OFF_X1B   16777216UL          // [8][256][256][32] bf16 (33554432 B)
#define OFF_AFFB  50331648UL          // [8][8][256][256]  bf16 (8388608 B)
#define OFF_W1FB  58720256UL          // [6][2][64][8] bf16 A-frag order (12288 B)
#define OFF_B1FB  58732544UL          // [32] fp32
#define OFF_W2FB  58732672UL          // [9][4][64][8] bf16 B-frag order (36864 B)
#define OFF_B2FB  58769536UL          // [64] fp32
#define OFF_W3FB  58769792UL          // [2][64][8] bf16 B-frag order (2048 B)

typedef short  short8 __attribute__((ext_vector_type(8)));
typedef ushort u16x8  __attribute__((ext_vector_type(8)));
typedef ushort u16x4  __attribute__((ext_vector_type(4)));
typedef float  f32x4  __attribute__((ext_vector_type(4)));

__device__ __forceinline__ ushort f2bf(float x) {
  uint u = __float_as_uint(x);
  return (ushort)((u + 0x7FFFu + ((u >> 16) & 1u)) >> 16);
}
__device__ __forceinline__ float bf2f(ushort h) {
  uint u = ((uint)h) << 16;
  return __uint_as_float(u);
}

// ---------------- feats (blocks < 1024, 2 px/thread) + weight prep (blocks >= 1024) ----------------
__global__ __launch_bounds__(256) void build_feats(
    const float* __restrict__ normal, const float* __restrict__ left,
    const float* __restrict__ right, const float* __restrict__ disp,
    const float* __restrict__ w1, const float* __restrict__ g1,
    const float* __restrict__ b1, const float* __restrict__ m1,
    const float* __restrict__ v1,
    const float* __restrict__ w2, const float* __restrict__ g2,
    const float* __restrict__ b2, const float* __restrict__ m2,
    const float* __restrict__ v2, const float* __restrict__ w3,
    char* __restrict__ wsb) {
  if (blockIdx.x >= 1024) {
    int idx = (blockIdx.x - 1024) * 256 + threadIdx.x;
    ushort* w1f = (ushort*)(wsb + OFF_W1FB);
    float* b1f  = (float*)(wsb + OFF_B1FB);
    ushort* w2f = (ushort*)(wsb + OFF_W2FB);
    float* b2f  = (float*)(wsb + OFF_B2FB);
    ushort* w3f = (ushort*)(wsb + OFF_W3FB);
    if (idx < 6144) {
      int jj = idx & 7;
      int lane = (idx >> 3) & 63;
      int mt = (idx >> 9) & 1;
      int s = idx >> 10;
      int ky = s >> 1, t = s & 1;
      int q = lane >> 4, lx = lane & 15;
      int k = q * 8 + jj;
      int dcol = k >> 4, ch = k & 15;
      int kx = t * 2 + dcol;
      int out = mt * 16 + lx;
      float inv = g1[out] / sqrtf(v1[out] + 1e-5f);
      float val = (ch < 12 && kx < 3) ? w1[((out * 12 + ch) * 3 + ky) * 3 + kx] * inv : 0.f;
      w1f[idx] = f2bf(val);
    }
    int j = idx - 6144;
    if (j >= 0 && j < 18432) {
      int kk   = j >> 11;
      int nt   = (j >> 9) & 3;
      int lane = (j >> 3) & 63;
      int jj   = j & 7;
      int q  = lane >> 4, lx = lane & 15;
      int cin = q * 8 + jj;
      int out = nt * 16 + lx;
      float inv = g2[out] / sqrtf(v2[out] + 1e-5f);
      w2f[j] = f2bf(w2[(out * 32 + cin) * 9 + kk] * inv);
      if (kk == 0 && q == 0 && jj == 0) b2f[out] = b2[out] - m2[out] * inv;
    }
    int k2 = idx - 24576;
    if (k2 >= 0 && k2 < 32) {
      float inv = g1[k2] / sqrtf(v1[k2] + 1e-5f);
      b1f[k2] = b1[k2] - m1[k2] * inv;
    }
    int k3 = idx - 24608;
    if (k3 >= 0 && k3 < 1024) {
      int jj = k3 & 7;
      int lane = (k3 >> 3) & 63;
      int slice = k3 >> 9;
      int q = lane >> 4, lx = lane & 15;
      int ch = slice * 32 + q * 8 + jj;
      w3f[k3] = (lx < 8) ? f2bf(w3[lx * 64 + ch]) : (ushort)0;
    }
    return;
  }
  int gid = blockIdx.x * 256 + threadIdx.x;   // 262144 threads, 2 px each
  int n = gid >> 15;
  int r = gid & 32767;
  int i = r >> 7;
  int jt = r & 127;
  int j0 = jt << 1;
  int i2 = i << 1;
  ushort* feats = (ushort*)(wsb + OFF_FEATS);
  ushort tmp[32];
#pragma unroll
  for (int c = 0; c < 3; ++c) {
    float2 nm = *(const float2*)(normal + (size_t)(n * 3 + c) * HW + i * 256 + j0);
    tmp[c] = f2bf(nm.x);
    tmp[16 + c] = f2bf(nm.y);
  }
  float cl[2][3];
#pragma unroll
  for (int c = 0; c < 3; ++c) {
    const float* Lp = left + ((size_t)(n * 3 + c) * 512 + i2) * 512 + (j0 << 1);
    float4 a0 = *(const float4*)Lp;
    float4 a1 = *(const float4*)(Lp + 512);
    cl[0][c] = 0.25f * (a0.x + a0.y + a1.x + a1.y);
    cl[1][c] = 0.25f * (a0.z + a0.w + a1.z + a1.w);
    tmp[3 + c] = f2bf(cl[0][c]);
    tmp[19 + c] = f2bf(cl[1][c]);
    const float* Rp = right + ((size_t)(n * 3 + c) * 512 + i2) * 512 + (j0 << 1);
    float4 b0 = *(const float4*)Rp;
    float4 b1v = *(const float4*)(Rp + 512);
    tmp[6 + c] = f2bf(0.25f * (b0.x + b0.y + b1v.x + b1v.y));
    tmp[22 + c] = f2bf(0.25f * (b0.z + b0.w + b1v.z + b1v.w));
  }
  float2 dp2 = *(const float2*)(disp + (size_t)n * HW + i * 256 + j0);
#pragma unroll
  for (int p = 0; p < 2; ++p) {
    int j = j0 + p;
    float d = p ? dp2.y : dp2.x;
    float xs = (float)j - d;
    float x0f = floorf(xs);
    float fr = xs - x0f;
    int ix0 = (int)x0f;
    int ix1 = ix0 + 1;
    float vm0 = (ix0 >= 0 && ix0 < WW) ? 1.f : 0.f;
    float vm1 = (ix1 >= 0 && ix1 < WW) ? 1.f : 0.f;
    int x0c = min(max(ix0, 0), WW - 1);
    int x1c = min(max(ix1, 0), WW - 1);
    bool adj = (x1c == x0c + 1);
    int xs2 = min(x0c + 1, WW - 1);
#pragma unroll
    for (int c = 0; c < 3; ++c) {
      const float* Rb = right + ((size_t)(n * 3 + c) * 512 + i2) * 512;
      float2 f0 = *(const float2*)(Rb + (x0c << 1));
      float2 f1 = *(const float2*)(Rb + (x0c << 1) + 512);
      float2 f2v = *(const float2*)(Rb + (xs2 << 1));
      float2 f3 = *(const float2*)(Rb + (xs2 << 1) + 512);
      float avg0 = 0.25f * (f0.x + f0.y + f1.x + f1.y);
      float avg1 = 0.25f * (f2v.x + f2v.y + f3.x + f3.y);
      float gg0 = avg0 * vm0;
      float gg1 = (adj ? avg1 : avg0) * vm1;
      float warped = gg0 * (1.f - fr) + gg1 * fr;
      tmp[p * 16 + 9 + c] = f2bf(fabsf(cl[p][c] - warped));
    }
  }
#pragma unroll
  for (int c = 12; c < 16; ++c) { tmp[c] = 0; tmp[16 + c] = 0; }
  size_t ob = ((size_t)(n * HW + i * 256 + j0)) * 16;
#pragma unroll
  for (int vv = 0; vv < 4; ++vv)
    *(u16x8*)&feats[ob + vv * 8] = *(u16x8*)&tmp[vv * 8];
}

// ---------------- conv1 (MFMA bf16): 3x3 12(->16)->32 -> NHWC32 bf16 ----------------
__global__ __launch_bounds__(256) void conv1_kernel(char* __restrict__ wsb) {
  __shared__ ushort tile[688 * 8];
  const ushort* __restrict__ feats = (const ushort*)(wsb + OFF_FEATS);
  const short8* __restrict__ w1fv = (const short8*)(wsb + OFF_W1FB);
  const float* __restrict__ b1f = (const float*)(wsb + OFF_B1FB);
  ushort* x1 = (ushort*)(wsb + OFF_X1B);
  int blk = blockIdx.x;
  int n = blk >> 8;
  int t = blk & 255;
  int ty0 = (t >> 4) << 4;
  int tx0 = (t & 15) << 4;
  int tid = threadIdx.x;
  int lane = tid & 63;
  int wid = tid >> 6;
  int q = lane >> 4;
  int lx = lane & 15;
  short8 aw[2][6];
#pragma unroll
  for (int s = 0; s < 6; ++s)
#pragma unroll
    for (int mt = 0; mt < 2; ++mt) aw[mt][s] = w1fv[(s * 2 + mt) * 64 + lane];
  for (int e = tid; e < 684; e += 256) {
    int row = e / 38;
    int rem = e - row * 38;
    int col = rem >> 1;
    int cc = rem & 1;
    int gy = ty0 + row - 1, gx = tx0 + col - 1;
    u16x8 v = (u16x8)0;
    if (gy >= 0 && gy < HH && gx >= 0 && gx < WW)
      v = *(const u16x8*)&feats[(((size_t)(n * 256 + gy)) * 256 + gx) * 16 + cc * 8];
    int slot = e ^ ((e >> 3) & 7);
    *(u16x8*)&tile[slot * 8] = v;
  }
  __syncthreads();
  short8 bfrag[6][2];
#pragma unroll
  for (int dr = 0; dr < 6; ++dr)
#pragma unroll
    for (int tt = 0; tt < 2; ++tt) {
      int prow = wid * 4 + dr;
      int G = (prow * 19 + lx + tt * 2 + (q >> 1)) * 2 + (q & 1);
      int slot = G ^ ((G >> 3) & 7);
      bfrag[dr][tt] = *(const short8*)&tile[slot * 8];
    }
  f32x4 acc[4][2];
#pragma unroll
  for (int rowt = 0; rowt < 4; ++rowt)
#pragma unroll
    for (int mt = 0; mt < 2; ++mt) acc[rowt][mt] = (f32x4)0.f;
#pragma unroll
  for (int s = 0; s < 6; ++s) {
    int ky = s >> 1;
    int tt = s & 1;
#pragma unroll
    for (int rowt = 0; rowt < 4; ++rowt) {
      short8 b = bfrag[rowt + ky][tt];
      acc[rowt][0] = __builtin_amdgcn_mfma_f32_16x16x32_bf16(aw[0][s], b, acc[rowt][0], 0, 0, 0);
      acc[rowt][1] = __builtin_amdgcn_mfma_f32_16x16x32_bf16(aw[1][s], b, acc[rowt][1], 0, 0, 0);
    }
  }
#pragma unroll
  for (int rowt = 0; rowt < 4; ++rowt) {
    int gy = ty0 + wid * 4 + rowt;
    int gx = tx0 + lx;
    size_t pb = (((size_t)(n * 256 + gy)) * 256 + gx) * 32;
#pragma unroll
    for (int mt = 0; mt < 2; ++mt) {
      u16x4 pack;
#pragma unroll
      for (int r = 0; r < 4; ++r) {
        int ch = mt * 16 + q * 4 + r;
        pack[r] = f2bf(fmaxf(acc[rowt][mt][r] + b1f[ch], 0.f));
      }
      *(u16x4*)&x1[pb + mt * 16 + q * 4] = pack;
    }
  }
}

// ---------------- conv2 (MFMA) + conv3 (MFMA) ----------------
__global__ __launch_bounds__(256) void conv2_kernel(char* __restrict__ wsb) {
  __shared__ ushort smem[256 * 68];
  const ushort* __restrict__ x1 = (const ushort*)(wsb + OFF_X1B);
  const short8* __restrict__ w2fv = (const short8*)(wsb + OFF_W2FB);
  const float* __restrict__ b2f = (const float*)(wsb + OFF_B2FB);
  const short8* __restrict__ w3fv = (const short8*)(wsb + OFF_W3FB);
  ushort* aff = (ushort*)(wsb + OFF_AFFB);

  int blk = blockIdx.x;
  int n = blk >> 8;
  int t = blk & 255;
  int ty0 = (t >> 4) << 4;
  int tx0 = (t & 15) << 4;
  int tid = threadIdx.x;
  int lane = tid & 63;
  int wid = tid >> 6;
  int q = lane >> 4;
  int lx = lane & 15;

  short8 bw3[2];
  bw3[0] = w3fv[lane];
  bw3[1] = w3fv[64 + lane];

  for (int e = tid; e < 1296; e += 256) {
    int p = e >> 2;
    int c = e & 3;
    int y = p / 18;
    int x = p - y * 18;
    int gy = ty0 + y - 1, gx = tx0 + x - 1;
    u16x8 val = (u16x8)0;
    if (gy >= 0 && gy < HH && gx >= 0 && gx < WW)
      val = *(const u16x8*)&x1[(((size_t)(n * 256 + gy)) * 256 + gx) * 32 + c * 8];
    *(u16x8*)&smem[p * 36 + c * 8] = val;
  }
  __syncthreads();

  f32x4 acc[4][4];
#pragma unroll
  for (int mt = 0; mt < 4; ++mt)
#pragma unroll
    for (int nt = 0; nt < 4; ++nt) acc[mt][nt] = (f32x4)0.f;

#pragma unroll
  for (int kk = 0; kk < 9; ++kk) {
    int ky = kk / 3, kx = kk - ky * 3;
    short8 a[4], b[4];
#pragma unroll
    for (int mt = 0; mt < 4; ++mt) {
      int row = wid * 4 + mt;
      a[mt] = *(const short8*)&smem[((row + ky) * 18 + lx + kx) * 36 + q * 8];
    }
#pragma unroll
    for (int nt = 0; nt < 4; ++nt) b[nt] = w2fv[(kk * 4 + nt) * 64 + lane];
#pragma unroll
    for (int mt = 0; mt < 4; ++mt)
#pragma unroll
      for (int nt = 0; nt < 4; ++nt)
        acc[mt][nt] = __builtin_amdgcn_mfma_f32_16x16x32_bf16(a[mt], b[nt], acc[mt][nt], 0, 0, 0);
  }

  __syncthreads();
#pragma unroll
  for (int nt = 0; nt < 4; ++nt) {
    float bias = b2f[nt * 16 + lx];
#pragma unroll
    for (int mt = 0; mt < 4; ++mt) {
      int row = wid * 4 + mt;
#pragma unroll
      for (int r = 0; r < 4; ++r) {
        int p = row * 16 + q * 4 + r;
        float v = fmaxf(acc[mt][nt][r] + bias, 0.f);
        smem[p * 68 + nt * 16 + lx] = f2bf(v);
      }
    }
  }
  __syncthreads();

  f32x4 acc3[4];
#pragma unroll
  for (int mt = 0; mt < 4; ++mt) acc3[mt] = (f32x4)0.f;
#pragma unroll
  for (int mt = 0; mt < 4; ++mt) {
    int p = wid * 64 + mt * 16 + lx;
#pragma unroll
    for (int s = 0; s < 2; ++s) {
      short8 a3 = *(const short8*)&smem[p * 68 + s * 32 + q * 8];
      acc3[mt] = __builtin_amdgcn_mfma_f32_16x16x32_bf16(a3, bw3[s], acc3[mt], 0, 0, 0);
    }
  }
  if (lx < 8) {
#pragma unroll
    for (int mt = 0; mt < 4; ++mt) {
      int py = ty0 + wid * 4 + mt;
      int px = tx0 + q * 4;
      u16x4 pk;
#pragma unroll
      for (int r = 0; r < 4; ++r) pk[r] = f2bf(fmaxf(acc3[mt][r], 0.f));
      *(u16x4*)&aff[((size_t)(n * 8 + lx)) * HW + (size_t)py * WW + px] = pk;
    }
  }
}

// ---------------- final: 8-neighbor softmax propagation, 4 px/thread ----------------
__global__ __launch_bounds__(256) void final_kernel(const float* __restrict__ disp,
                                                    const char* __restrict__ wsb,
                                                    float* __restrict__ out) {
  int gid = blockIdx.x * 256 + threadIdx.x;  // 131072 threads
  int n = gid >> 14;
  int r = gid & 16383;
  int i = r >> 6;
  int j0 = (r & 63) << 2;
  const ushort* aff = (const ushort*)(wsb + OFF_AFFB);
  // disp windows rows i-1,i,i+1, cols j0-1..j0+4
  float d6[3][6];
#pragma unroll
  for (int rr = 0; rr < 3; ++rr) {
    int y = min(max(i + rr - 1, 0), HH - 1);
    const float* dp = disp + (size_t)n * HW + y * WW;
    float4 c4 = *(const float4*)(dp + j0);
    d6[rr][1] = c4.x; d6[rr][2] = c4.y; d6[rr][3] = c4.z; d6[rr][4] = c4.w;
    d6[rr][0] = dp[max(j0 - 1, 0)];
    d6[rr][5] = dp[min(j0 + 4, WW - 1)];
  }
  const int dy[8] = {1, 1, 1, 0, 0, -1, -1, -1};
  const int dx[8] = {1, 0, -1, 1, -1, 1, 0, -1};
  float g[8][4], dvv[8][4];
#pragma unroll
  for (int k = 0; k < 8; ++k) {
    int y = i + dy[k];
    bool vy = (y >= 0 && y < HH);
    int yc = min(max(y, 0), HH - 1);
    const ushort* ap = aff + ((size_t)(n * 8 + k)) * HW + (size_t)yc * WW;
    float w6[6];
    u16x4 c4 = *(const u16x4*)(ap + j0);
    w6[1] = bf2f(c4[0]); w6[2] = bf2f(c4[1]); w6[3] = bf2f(c4[2]); w6[4] = bf2f(c4[3]);
    w6[0] = bf2f(ap[max(j0 - 1, 0)]);
    w6[5] = bf2f(ap[min(j0 + 4, WW - 1)]);
    int rr = dy[k] + 1;
#pragma unroll
    for (int p = 0; p < 4; ++p) {
      int xp = j0 + p + dx[k];
      bool ok = vy && (xp >= 0) && (xp < WW);
      g[k][p] = ok ? w6[p + 1 + dx[k]] : 0.f;
      dvv[k][p] = ok ? d6[rr][p + 1 + dx[k]] : 0.f;
    }
  }
  float4 res;
#pragma unroll
  for (int p = 0; p < 4; ++p) {
    float m = g[0][p];
#pragma unroll
    for (int k = 1; k < 8; ++k) m = fmaxf(m, g[k][p]);
    float se = 0.f, sed = 0.f;
#pragma unroll
    for (int k = 0; k < 8; ++k) {
      float e = __expf(g[k][p] - m);
      se += e;
      sed += e * dvv[k][p];
    }
    float dc = d6[1][p + 1];
    (&res.x)[p] = 0.3f * (sed / se) + 0.7f * dc;
  }
  *(float4*)(out + (size_t)n * HW + i * WW + j0) = res;
}

extern "C" void kernel_launch(void* const* d_in, const int* in_sizes, int n_in,
                              void* d_out, int out_size, void* d_ws, size_t ws_size,
                              hipStream_t stream) {
  const float* normal = (const float*)d_in[0];
  const float* left   = (const float*)d_in[1];
  const float* right  = (const float*)d_in[2];
  const float* disp   = (const float*)d_in[3];
  const float* w1 = (const float*)d_in[4];
  const float* g1 = (const float*)d_in[5];
  const float* b1 = (const float*)d_in[6];
  const float* m1 = (const float*)d_in[7];
  const float* v1 = (const float*)d_in[8];
  const float* w2 = (const float*)d_in[9];
  const float* g2 = (const float*)d_in[10];
  const float* b2 = (const float*)d_in[11];
  const float* m2 = (const float*)d_in[12];
  const float* v2 = (const float*)d_in[13];
  const float* w3 = (const float*)d_in[14];
  char* wsb  = (char*)d_ws;
  float* out = (float*)d_out;

  hipLaunchKernelGGL(build_feats, dim3(1125), dim3(256), 0, stream,
                     normal, left, right, disp,
                     w1, g1, b1, m1, v1, w2, g2, b2, m2, v2, w3, wsb);
  hipLaunchKernelGGL(conv1_kernel, dim3(2048), dim3(256), 0, stream, wsb);
  hipLaunchKernelGGL(conv2_kernel, dim3(2048), dim3(256), 0, stream, wsb);
  hipLaunchKernelGGL(final_kernel, dim3(512), dim3(256), 0, stream, disp, wsb, out);
}